// Round 7
// baseline (178.032 us; speedup 1.0000x reference)
//
#include <hip/hip_runtime.h>
#include <math.h>

// TM-score. S=1024 samples, L=4096 residues, fp32.
// K0: transpose tru -> SoA [3][L] + mask -> float[L]   (tiny, one-time)
// K1: fused main, one block/sample, 256 threads:
//     - pred sample (48 KB) staged ONCE coalesced into LDS (b128 reads,
//       conflict-free at 48 B/lane stride — verified SQ_LDS_BANK_CONFLICT=0)
//     - tru/mask read as lane-contiguous float4 from SoA ws (L2-hot)
//     - solve: per-thread redundant fp32 Jacobi on 4x4 Horn matrix,
//       FULLY UNROLLED (R6 lesson: runtime p/q indices -> cndmask trees,
//       ~16k VALU instr/thread; unrolled ~2k)
// LDS 48.3 KB -> 3 blocks/CU.

#define NS   1024
#define NL   4096
#define TPB  256
#define NCHUNK 4
#define CHUNK_RES (NL / NCHUNK)   // 1024 residues/chunk, 4/thread

// ws layout (floats): truT[3][NL] then wmask[NL]
#define WS_T_OFF 0
#define WS_W_OFF (3 * NL)

__device__ __forceinline__ float waveReduceSum(float v) {
    #pragma unroll
    for (int off = 32; off > 0; off >>= 1)
        v += __shfl_down(v, off, 64);
    return v;
}

// ---------------- K0: SoA transpose of tru + mask ----------------
__global__ __launch_bounds__(TPB) void k0_soa(
    const float* __restrict__ tru, const int* __restrict__ mask,
    float* __restrict__ ws)
{
    const int l = blockIdx.x * TPB + threadIdx.x;
    if (l >= NL) return;
    ws[WS_T_OFF + 0 * NL + l] = tru[l * 3 + 0];
    ws[WS_T_OFF + 1 * NL + l] = tru[l * 3 + 1];
    ws[WS_T_OFF + 2 * NL + l] = tru[l * 3 + 2];
    ws[WS_W_OFF + l] = mask[l] ? 1.0f : 0.0f;
}

// ---------------- K1: fused main ----------------
__global__ __launch_bounds__(TPB, 4) void tm_fused(
    const float* __restrict__ pred, const float* __restrict__ ws,
    float* __restrict__ out)
{
    const int s    = blockIdx.x;
    const int tid  = threadIdx.x;
    const int wave = tid >> 6, lane = tid & 63;
    const float* ps = pred + (size_t)s * NL * 3;

    __shared__ float ldsP[NL * 3];          // 48 KB: whole pred sample
    __shared__ float sred[4][16];

    // ---- stage pred once, coalesced ----
    {
        const float4* gp = (const float4*)ps;
        float4* lp = (float4*)ldsP;
        #pragma unroll
        for (int j = 0; j < 12; ++j) {
            const int idx = j * TPB + tid;
            lp[idx] = gp[idx];
        }
    }
    __syncthreads();

    // acc: [0]=Lt [1..3]=St [4..6]=Sp [7..15]=C[i][j]=sum w*p_i*t_j
    float acc[16];
    #pragma unroll
    for (int i = 0; i < 16; ++i) acc[i] = 0.f;

    // ---------------- Phase 1: covariance sums ----------------
    #pragma unroll
    for (int k = 0; k < NCHUNK; ++k) {
        const int rbase = k * CHUNK_RES + tid * 4;
        const float4* rp = (const float4*)&ldsP[rbase * 3];
        const float4 q0 = rp[0], q1 = rp[1], q2 = rp[2];
        const float4 tX = *(const float4*)(ws + WS_T_OFF + 0 * NL + rbase);
        const float4 tY = *(const float4*)(ws + WS_T_OFF + 1 * NL + rbase);
        const float4 tZ = *(const float4*)(ws + WS_T_OFF + 2 * NL + rbase);
        const float4 wV = *(const float4*)(ws + WS_W_OFF + rbase);

        const float px[4] = {q0.x, q0.w, q1.z, q2.y};
        const float py[4] = {q0.y, q1.x, q1.w, q2.z};
        const float pz[4] = {q0.z, q1.y, q2.x, q2.w};
        const float tx[4] = {tX.x, tX.y, tX.z, tX.w};
        const float ty[4] = {tY.x, tY.y, tY.z, tY.w};
        const float tz[4] = {tZ.x, tZ.y, tZ.z, tZ.w};
        const float wm[4] = {wV.x, wV.y, wV.z, wV.w};

        #pragma unroll
        for (int r = 0; r < 4; ++r) {
            const float w = wm[r];
            const float wpx = w * px[r], wpy = w * py[r], wpz = w * pz[r];
            acc[0] += w;
            acc[1] += w * tx[r]; acc[2] += w * ty[r]; acc[3] += w * tz[r];
            acc[4] += wpx; acc[5] += wpy; acc[6] += wpz;
            acc[7]  += wpx * tx[r]; acc[8]  += wpx * ty[r]; acc[9]  += wpx * tz[r];
            acc[10] += wpy * tx[r]; acc[11] += wpy * ty[r]; acc[12] += wpy * tz[r];
            acc[13] += wpz * tx[r]; acc[14] += wpz * ty[r]; acc[15] += wpz * tz[r];
        }
    }

    #pragma unroll
    for (int i = 0; i < 16; ++i) {
        float r = waveReduceSum(acc[i]);
        if (lane == 0) sred[wave][i] = r;
    }
    __syncthreads();

    // ------- Solve (all threads, identical): fp64 H + fp32 Jacobi -------
    double S[16];
    #pragma unroll
    for (int i = 0; i < 16; ++i)
        S[i] = (double)sred[0][i] + (double)sred[1][i]
             + (double)sred[2][i] + (double)sred[3][i];

    const double Lt = S[0], invLt = 1.0 / Lt;
    const double tmxd = S[1]*invLt, tmyd = S[2]*invLt, tmzd = S[3]*invLt;
    const double pmxd = S[4]*invLt, pmyd = S[5]*invLt, pmzd = S[6]*invLt;

    float H[3][3];
    {
        const double Sp[3] = {S[4], S[5], S[6]};
        const double St[3] = {S[1], S[2], S[3]};
        #pragma unroll
        for (int i = 0; i < 3; ++i)
            #pragma unroll
            for (int j = 0; j < 3; ++j)
                H[i][j] = (float)((S[7 + i*3 + j] - Sp[i]*St[j]*invLt) * invLt);
    }

    const float Sxx=H[0][0], Sxy=H[0][1], Sxz=H[0][2];
    const float Syx=H[1][0], Syy=H[1][1], Syz=H[1][2];
    const float Szx=H[2][0], Szy=H[2][1], Szz=H[2][2];
    float A[4][4] = {
      { Sxx+Syy+Szz, Syz-Szy,      Szx-Sxz,      Sxy-Syx      },
      { Syz-Szy,     Sxx-Syy-Szz,  Sxy+Syx,      Szx+Sxz      },
      { Szx-Sxz,     Sxy+Syx,      Syy-Sxx-Szz,  Syz+Szy      },
      { Sxy-Syx,     Szx+Sxz,      Syz+Szy,      Szz-Sxx-Syy  }
    };
    float V[4][4] = {{1,0,0,0},{0,1,0,0},{0,0,1,0},{0,0,0,1}};

    #pragma unroll
    for (int sweep = 0; sweep < 6; ++sweep) {
        #pragma unroll
        for (int p = 0; p < 3; ++p) {
            #pragma unroll
            for (int q = p + 1; q < 4; ++q) {
                const float apq = A[p][q];
                if (fabsf(apq) >= 1e-30f) {
                    const float tau = (A[q][q] - A[p][p]) / (2.0f * apq);
                    const float tt  = (tau >= 0.0f ? 1.0f : -1.0f)
                                      / (fabsf(tau) + sqrtf(1.0f + tau*tau));
                    const float cc  = 1.0f / sqrtf(1.0f + tt*tt);
                    const float sn  = tt * cc;
                    #pragma unroll
                    for (int m = 0; m < 4; ++m) {
                        const float akp = A[m][p], akq = A[m][q];
                        A[m][p] = cc*akp - sn*akq;
                        A[m][q] = sn*akp + cc*akq;
                    }
                    #pragma unroll
                    for (int m = 0; m < 4; ++m) {
                        const float apk = A[p][m], aqk = A[q][m];
                        A[p][m] = cc*apk - sn*aqk;
                        A[q][m] = sn*apk + cc*aqk;
                    }
                    #pragma unroll
                    for (int m = 0; m < 4; ++m) {
                        const float vkp = V[m][p], vkq = V[m][q];
                        V[m][p] = cc*vkp - sn*vkq;
                        V[m][q] = sn*vkp + cc*vkq;
                    }
                }
            }
        }
    }
    int imax = 0;
    #pragma unroll
    for (int i = 1; i < 4; ++i) if (A[i][i] > A[imax][imax]) imax = i;
    const float q0f = V[0][imax], qxf = V[1][imax], qyf = V[2][imax], qzf = V[3][imax];

    const float R00 = q0f*q0f+qxf*qxf-qyf*qyf-qzf*qzf;
    const float R01 = 2.0f*(qxf*qyf - q0f*qzf);
    const float R02 = 2.0f*(qxf*qzf + q0f*qyf);
    const float R10 = 2.0f*(qyf*qxf + q0f*qzf);
    const float R11 = q0f*q0f-qxf*qxf+qyf*qyf-qzf*qzf;
    const float R12 = 2.0f*(qyf*qzf - q0f*qxf);
    const float R20 = 2.0f*(qzf*qxf - q0f*qyf);
    const float R21 = 2.0f*(qzf*qyf + q0f*qxf);
    const float R22 = q0f*q0f-qxf*qxf-qyf*qyf+qzf*qzf;

    double d0 = (Lt <= 15.0) ? 0.5 : (1.24 * cbrt(Lt - 15.0) - 1.8);
    if (d0 < 0.5) d0 = 0.5;
    const float inv_d0sq = (float)(1.0 / (d0 * d0));
    const float invLtf   = (float)invLt;
    const float pmx = (float)pmxd, pmy = (float)pmyd, pmz = (float)pmzd;
    const float tmx = (float)tmxd, tmy = (float)tmyd, tmz = (float)tmzd;

    // ------- Phase 2: pred from LDS, tru/mask coalesced SoA -------
    float tacc = 0.f;
    #pragma unroll
    for (int k = 0; k < NCHUNK; ++k) {
        const int rbase = k * CHUNK_RES + tid * 4;
        const float4* rp = (const float4*)&ldsP[rbase * 3];
        const float4 q0 = rp[0], q1 = rp[1], q2 = rp[2];
        const float4 tX = *(const float4*)(ws + WS_T_OFF + 0 * NL + rbase);
        const float4 tY = *(const float4*)(ws + WS_T_OFF + 1 * NL + rbase);
        const float4 tZ = *(const float4*)(ws + WS_T_OFF + 2 * NL + rbase);
        const float4 wV = *(const float4*)(ws + WS_W_OFF + rbase);

        const float px[4] = {q0.x, q0.w, q1.z, q2.y};
        const float py[4] = {q0.y, q1.x, q1.w, q2.z};
        const float pz[4] = {q0.z, q1.y, q2.x, q2.w};
        const float tx[4] = {tX.x, tX.y, tX.z, tX.w};
        const float ty[4] = {tY.x, tY.y, tY.z, tY.w};
        const float tz[4] = {tZ.x, tZ.y, tZ.z, tZ.w};
        const float wm[4] = {wV.x, wV.y, wV.z, wV.w};

        #pragma unroll
        for (int r = 0; r < 4; ++r) {
            const float vx = px[r] - pmx, vy = py[r] - pmy, vz = pz[r] - pmz;
            const float a0 = R00*vx + R01*vy + R02*vz + tmx - tx[r];
            const float a1 = R10*vx + R11*vy + R12*vz + tmy - ty[r];
            const float a2 = R20*vx + R21*vy + R22*vz + tmz - tz[r];
            const float dsq = a0*a0 + a1*a1 + a2*a2;
            tacc += wm[r] * __builtin_amdgcn_rcpf(1.0f + dsq * inv_d0sq);
        }
    }
    tacc *= invLtf;

    float r = waveReduceSum(tacc);
    if (lane == 0) sred[wave][0] = r;
    __syncthreads();
    if (tid == 0)
        out[s] = sred[0][0] + sred[1][0] + sred[2][0] + sred[3][0];
}

extern "C" void kernel_launch(void* const* d_in, const int* in_sizes, int n_in,
                              void* d_out, int out_size, void* d_ws, size_t ws_size,
                              hipStream_t stream) {
    const float* pred = (const float*)d_in[0];
    const float* tru  = (const float*)d_in[1];
    const int*   mask = (const int*)d_in[2];
    float* out = (float*)d_out;
    float* ws  = (float*)d_ws;

    k0_soa  <<<NL / TPB, TPB, 0, stream>>>(tru, mask, ws);
    tm_fused<<<NS, TPB, 0, stream>>>(pred, ws, out);
}

// Round 8
// 102.328 us; speedup vs baseline: 1.7398x; 1.7398x over previous
//
#include <hip/hip_runtime.h>
#include <math.h>

// TM-score. S=1024 samples, L=4096 residues, fp32.
// K0: transpose tru -> SoA [3][L] + mask -> float[L] in ws  (tiny)
// K1: fused main, one block/sample, 256 threads, 4 chunks x 4 res/thread:
//   - per chunk: stage pred chunk (12 KB) coalesced -> LDS, consume at
//     48 B/lane stride (b128, conflict-free: SQ_LDS_BANK_CONFLICT=0 measured)
//   - tru/mask read lane-contiguous float4 from SoA ws (no LDS needed)
//   - solve: per-thread redundant fp64 QCP: Newton on quartic char poly
//     from GERSHGORIN upper bound (R4 bug: far start never converged),
//     eigenvector via adjugate row. ~300 flops, all constant-indexed.
//   - phase 2 re-stages pred chunks (L3/HBM re-read; measured better than
//     whole-pred-in-LDS which halves occupancy: R4=34us vs R6=88us)
// LDS ~12.3 KB -> 7-8 blocks/CU (occupancy is king: kernel is latency-bound,
// the harness's 256 MiB poison-fill evicts L3 + drains writebacks under us).

#define NS   1024
#define NL   4096
#define TPB  256
#define NCHUNK 4
#define CHUNK_RES (NL / NCHUNK)   // 1024 residues/chunk, 4/thread

// ws layout (floats): truT[3][NL] then wmask[NL]
#define WS_T_OFF 0
#define WS_W_OFF (3 * NL)

__device__ __forceinline__ float waveReduceSum(float v) {
    #pragma unroll
    for (int off = 32; off > 0; off >>= 1)
        v += __shfl_down(v, off, 64);
    return v;
}

__device__ __forceinline__ double det3(const double B[4][4],
                                       int r0, int r1, int r2,
                                       int c0, int c1, int c2) {
    return B[r0][c0]*(B[r1][c1]*B[r2][c2] - B[r1][c2]*B[r2][c1])
         - B[r0][c1]*(B[r1][c0]*B[r2][c2] - B[r1][c2]*B[r2][c0])
         + B[r0][c2]*(B[r1][c0]*B[r2][c1] - B[r1][c1]*B[r2][c0]);
}

// ---------------- K0: SoA transpose of tru + mask ----------------
__global__ __launch_bounds__(TPB) void k0_soa(
    const float* __restrict__ tru, const int* __restrict__ mask,
    float* __restrict__ ws)
{
    const int l = blockIdx.x * TPB + threadIdx.x;
    if (l >= NL) return;
    ws[WS_T_OFF + 0 * NL + l] = tru[l * 3 + 0];
    ws[WS_T_OFF + 1 * NL + l] = tru[l * 3 + 1];
    ws[WS_T_OFF + 2 * NL + l] = tru[l * 3 + 2];
    ws[WS_W_OFF + l] = mask[l] ? 1.0f : 0.0f;
}

// ---------------- K1: fused main ----------------
__global__ __launch_bounds__(TPB, 4) void tm_fused(
    const float* __restrict__ pred, const float* __restrict__ ws,
    float* __restrict__ out)
{
    const int s    = blockIdx.x;
    const int tid  = threadIdx.x;
    const int wave = tid >> 6, lane = tid & 63;
    const float* ps = pred + (size_t)s * NL * 3;

    __shared__ float ldsP[CHUNK_RES * 3];   // 12 KB
    __shared__ float sred[4][16];

    // acc: [0]=Lt [1..3]=St [4..6]=Sp [7..15]=C[i][j]=sum w*p_i*t_j
    float acc[16];
    #pragma unroll
    for (int i = 0; i < 16; ++i) acc[i] = 0.f;

    // ---------------- Phase 1: covariance sums ----------------
    for (int k = 0; k < NCHUNK; ++k) {
        const float4* gp = (const float4*)(ps + (size_t)k * CHUNK_RES * 3);
        float4* lp = (float4*)ldsP;
        #pragma unroll
        for (int j = 0; j < 3; ++j) {       // 768 float4 / 256 thr, coalesced
            const int idx = j * TPB + tid;
            lp[idx] = gp[idx];
        }
        __syncthreads();

        const int rbase = k * CHUNK_RES + tid * 4;
        const float4* rp = (const float4*)&ldsP[tid * 12];
        const float4 q0 = rp[0], q1 = rp[1], q2 = rp[2];
        const float4 tX = *(const float4*)(ws + WS_T_OFF + 0 * NL + rbase);
        const float4 tY = *(const float4*)(ws + WS_T_OFF + 1 * NL + rbase);
        const float4 tZ = *(const float4*)(ws + WS_T_OFF + 2 * NL + rbase);
        const float4 wV = *(const float4*)(ws + WS_W_OFF + rbase);

        const float px[4] = {q0.x, q0.w, q1.z, q2.y};
        const float py[4] = {q0.y, q1.x, q1.w, q2.z};
        const float pz[4] = {q0.z, q1.y, q2.x, q2.w};
        const float tx[4] = {tX.x, tX.y, tX.z, tX.w};
        const float ty[4] = {tY.x, tY.y, tY.z, tY.w};
        const float tz[4] = {tZ.x, tZ.y, tZ.z, tZ.w};
        const float wm[4] = {wV.x, wV.y, wV.z, wV.w};

        #pragma unroll
        for (int r = 0; r < 4; ++r) {
            const float w = wm[r];
            const float wpx = w * px[r], wpy = w * py[r], wpz = w * pz[r];
            acc[0] += w;
            acc[1] += w * tx[r]; acc[2] += w * ty[r]; acc[3] += w * tz[r];
            acc[4] += wpx; acc[5] += wpy; acc[6] += wpz;
            acc[7]  += wpx * tx[r]; acc[8]  += wpx * ty[r]; acc[9]  += wpx * tz[r];
            acc[10] += wpy * tx[r]; acc[11] += wpy * ty[r]; acc[12] += wpy * tz[r];
            acc[13] += wpz * tx[r]; acc[14] += wpz * ty[r]; acc[15] += wpz * tz[r];
        }
        __syncthreads();   // before next chunk overwrites LDS
    }

    #pragma unroll
    for (int i = 0; i < 16; ++i) {
        float r = waveReduceSum(acc[i]);
        if (lane == 0) sred[wave][i] = r;
    }
    __syncthreads();

    // ---- Solve (all threads, identical): fp64 QCP ----
    double S[16];
    #pragma unroll
    for (int i = 0; i < 16; ++i)
        S[i] = (double)sred[0][i] + (double)sred[1][i]
             + (double)sred[2][i] + (double)sred[3][i];

    const double Lt = S[0], invLt = 1.0 / Lt;
    const double tmxd = S[1]*invLt, tmyd = S[2]*invLt, tmzd = S[3]*invLt;
    const double pmxd = S[4]*invLt, pmyd = S[5]*invLt, pmzd = S[6]*invLt;

    double H[3][3];
    {
        const double Sp[3] = {S[4], S[5], S[6]};
        const double St[3] = {S[1], S[2], S[3]};
        #pragma unroll
        for (int i = 0; i < 3; ++i)
            #pragma unroll
            for (int j = 0; j < 3; ++j)
                H[i][j] = (S[7 + i*3 + j] - Sp[i]*St[j]*invLt) * invLt;
    }

    const double Sxx=H[0][0], Sxy=H[0][1], Sxz=H[0][2];
    const double Syx=H[1][0], Syy=H[1][1], Syz=H[1][2];
    const double Szx=H[2][0], Szy=H[2][1], Szz=H[2][2];
    double K[4][4] = {
      { Sxx+Syy+Szz, Syz-Szy,      Szx-Sxz,      Sxy-Syx      },
      { Syz-Szy,     Sxx-Syy-Szz,  Sxy+Syx,      Szx+Sxz      },
      { Szx-Sxz,     Sxy+Syx,      Syy-Sxx-Szz,  Syz+Szy      },
      { Sxy-Syx,     Szx+Sxz,      Syz+Szy,      Szz-Sxx-Syy  }
    };

    // char poly det(lam I - K) = lam^4 + E2 lam^2 - E3 lam + E4  (tr K = 0)
    double E2 = 0.0;
    #pragma unroll
    for (int i = 0; i < 4; ++i)
        #pragma unroll
        for (int j = 0; j < 4; ++j)
            if (j > i) E2 += K[i][i]*K[j][j] - K[i][j]*K[i][j];
    const double M123 = det3(K,1,2,3, 1,2,3);
    const double E3 = M123 + det3(K,0,2,3, 0,2,3)
                    + det3(K,0,1,3, 0,1,3) + det3(K,0,1,2, 0,1,2);
    const double E4 = K[0][0]*M123 - K[0][1]*det3(K,1,2,3, 0,2,3)
                    + K[0][2]*det3(K,1,2,3, 0,1,3) - K[0][3]*det3(K,1,2,3, 0,1,2);

    // Gershgorin upper bound on lambda_max (tight for near-zero K; the
    // R4 start 0.5*(gA+gB) was ~100x too high -> Newton never converged)
    double lam = 0.0;
    #pragma unroll
    for (int i = 0; i < 4; ++i) {
        const double rs = fabs(K[i][0]) + fabs(K[i][1])
                        + fabs(K[i][2]) + fabs(K[i][3]);
        lam = fmax(lam, rs);
    }
    #pragma unroll
    for (int it = 0; it < 15; ++it) {
        const double l2 = lam * lam;
        const double P  = ((l2 + E2) * lam - E3) * lam + E4;
        const double Pd = (4.0 * l2 + 2.0 * E2) * lam - E3;
        lam -= P / Pd;     // monotone from above; Pd > 0 right of lam_max
    }

    // eigenvector = largest-norm row of adj(K - lam I)
    #pragma unroll
    for (int i = 0; i < 4; ++i) K[i][i] -= lam;
    double best[4] = {1.0, 0.0, 0.0, 0.0};
    double bestn = -1.0;
    #pragma unroll
    for (int r = 0; r < 4; ++r) {
        const int r0 = (r==0)?1:0, r1 = (r<=1)?2:1, r2 = (r<=2)?3:2;
        double v[4];
        #pragma unroll
        for (int c = 0; c < 4; ++c) {
            const int c0 = (c==0)?1:0, c1 = (c<=1)?2:1, c2 = (c<=2)?3:2;
            const double d = det3(K, r0,r1,r2, c0,c1,c2);
            v[c] = ((r + c) & 1) ? -d : d;
        }
        const double n = v[0]*v[0]+v[1]*v[1]+v[2]*v[2]+v[3]*v[3];
        if (n > bestn) { bestn = n; best[0]=v[0]; best[1]=v[1]; best[2]=v[2]; best[3]=v[3]; }
    }
    const double qn = 1.0 / sqrt(bestn);
    const double q0d = best[0]*qn, qxd = best[1]*qn, qyd = best[2]*qn, qzd = best[3]*qn;

    const float R00 = (float)(q0d*q0d+qxd*qxd-qyd*qyd-qzd*qzd);
    const float R01 = (float)(2.0*(qxd*qyd - q0d*qzd));
    const float R02 = (float)(2.0*(qxd*qzd + q0d*qyd));
    const float R10 = (float)(2.0*(qyd*qxd + q0d*qzd));
    const float R11 = (float)(q0d*q0d-qxd*qxd+qyd*qyd-qzd*qzd);
    const float R12 = (float)(2.0*(qyd*qzd - q0d*qxd));
    const float R20 = (float)(2.0*(qzd*qxd - q0d*qyd));
    const float R21 = (float)(2.0*(qzd*qyd + q0d*qxd));
    const float R22 = (float)(q0d*q0d-qxd*qxd-qyd*qyd+qzd*qzd);

    double d0 = (Lt <= 15.0) ? 0.5 : (1.24 * cbrt(Lt - 15.0) - 1.8);
    if (d0 < 0.5) d0 = 0.5;
    const float inv_d0sq = (float)(1.0 / (d0 * d0));
    const float invLtf   = (float)invLt;
    const float pmx = (float)pmxd, pmy = (float)pmyd, pmz = (float)pmzd;
    const float tmx = (float)tmxd, tmy = (float)tmyd, tmz = (float)tmzd;

    // ------- Phase 2: re-stage pred chunks; tru/mask coalesced SoA -------
    float tacc = 0.f;
    for (int k = 0; k < NCHUNK; ++k) {
        __syncthreads();
        const float4* gp = (const float4*)(ps + (size_t)k * CHUNK_RES * 3);
        float4* lp = (float4*)ldsP;
        #pragma unroll
        for (int j = 0; j < 3; ++j) {
            const int idx = j * TPB + tid;
            lp[idx] = gp[idx];
        }
        __syncthreads();

        const int rbase = k * CHUNK_RES + tid * 4;
        const float4* rp = (const float4*)&ldsP[tid * 12];
        const float4 q0 = rp[0], q1 = rp[1], q2 = rp[2];
        const float4 tX = *(const float4*)(ws + WS_T_OFF + 0 * NL + rbase);
        const float4 tY = *(const float4*)(ws + WS_T_OFF + 1 * NL + rbase);
        const float4 tZ = *(const float4*)(ws + WS_T_OFF + 2 * NL + rbase);
        const float4 wV = *(const float4*)(ws + WS_W_OFF + rbase);

        const float px[4] = {q0.x, q0.w, q1.z, q2.y};
        const float py[4] = {q0.y, q1.x, q1.w, q2.z};
        const float pz[4] = {q0.z, q1.y, q2.x, q2.w};
        const float tx[4] = {tX.x, tX.y, tX.z, tX.w};
        const float ty[4] = {tY.x, tY.y, tY.z, tY.w};
        const float tz[4] = {tZ.x, tZ.y, tZ.z, tZ.w};
        const float wm[4] = {wV.x, wV.y, wV.z, wV.w};

        #pragma unroll
        for (int r = 0; r < 4; ++r) {
            const float vx = px[r] - pmx, vy = py[r] - pmy, vz = pz[r] - pmz;
            const float a0 = R00*vx + R01*vy + R02*vz + tmx - tx[r];
            const float a1 = R10*vx + R11*vy + R12*vz + tmy - ty[r];
            const float a2 = R20*vx + R21*vy + R22*vz + tmz - tz[r];
            const float dsq = a0*a0 + a1*a1 + a2*a2;
            tacc += wm[r] * __builtin_amdgcn_rcpf(1.0f + dsq * inv_d0sq);
        }
    }
    tacc *= invLtf;

    float r = waveReduceSum(tacc);
    if (lane == 0) sred[wave][0] = r;
    __syncthreads();
    if (tid == 0)
        out[s] = sred[0][0] + sred[1][0] + sred[2][0] + sred[3][0];
}

extern "C" void kernel_launch(void* const* d_in, const int* in_sizes, int n_in,
                              void* d_out, int out_size, void* d_ws, size_t ws_size,
                              hipStream_t stream) {
    const float* pred = (const float*)d_in[0];
    const float* tru  = (const float*)d_in[1];
    const int*   mask = (const int*)d_in[2];
    float* out = (float*)d_out;
    float* ws  = (float*)d_ws;

    k0_soa  <<<NL / TPB, TPB, 0, stream>>>(tru, mask, ws);
    tm_fused<<<NS, TPB, 0, stream>>>(pred, ws, out);
}